// Round 2
// baseline (202.339 us; speedup 1.0000x reference)
//
#include <hip/hip_runtime.h>

// Problem constants (from reference): B=8, N=16384, S=1024, T=2, D=3
#define NPTS 16384
#define SPTS 1024

// Combined batch index bb in [0,24): bb<8 -> chamfer1 (structure vs gt),
// bb>=8 -> chamfer2 on reshaped transed arrays (16 "batches").

// Pass A: for each gt point, min over all 1024 structure points of that batch.
// dist = |q|^2 + (|s|^2 - 2 q.s); we min the parenthesized part (3 FMA + min).
__global__ __launch_bounds__(256) void chamfer_minA(
    const float* __restrict__ gt,   // [8,16384,3]
    const float* __restrict__ sp,   // [8,1024,3]
    const float* __restrict__ tgt,  // [16,16384,3]
    const float* __restrict__ tsp,  // [16,1024,3]
    float* __restrict__ accum)
{
    __shared__ float4 s_ref[SPTS];  // 16 KB
    const int bb   = blockIdx.x;        // 0..23
    const int tile = blockIdx.y;        // 0..31 (512 gt points each)
    const float* refp = (bb < 8) ? (sp + (size_t)bb * SPTS * 3)
                                 : (tsp + (size_t)(bb - 8) * SPTS * 3);
    const float* qp   = (bb < 8) ? (gt + (size_t)bb * NPTS * 3)
                                 : (tgt + (size_t)(bb - 8) * NPTS * 3);
    const int tid = threadIdx.x;

    for (int i = tid; i < SPTS; i += 256) {
        float x = refp[i * 3 + 0], y = refp[i * 3 + 1], z = refp[i * 3 + 2];
        s_ref[i] = make_float4(x, y, z, x * x + y * y + z * z);
    }
    __syncthreads();

    float qx2[2], qy2[2], qz2[2], qs[2], mn[2];
#pragma unroll
    for (int g = 0; g < 2; g++) {
        int q = tile * 512 + g * 256 + tid;
        float x = qp[q * 3 + 0], y = qp[q * 3 + 1], z = qp[q * 3 + 2];
        qx2[g] = -2.f * x; qy2[g] = -2.f * y; qz2[g] = -2.f * z;
        qs[g] = x * x + y * y + z * z;
        mn[g] = 1e30f;
    }

#pragma unroll 4
    for (int j = 0; j < SPTS; j++) {
        float4 s = s_ref[j];  // wave-uniform address -> LDS broadcast, no conflicts
#pragma unroll
        for (int g = 0; g < 2; g++) {
            float d = fmaf(qx2[g], s.x, fmaf(qy2[g], s.y, fmaf(qz2[g], s.z, s.w)));
            mn[g] = fminf(mn[g], d);
        }
    }

    float v = (qs[0] + mn[0]) + (qs[1] + mn[1]);
    for (int o = 32; o > 0; o >>= 1) v += __shfl_down(v, o, 64);
    if ((tid & 63) == 0) {
        // mean over per-gt mins, /2 (chamfer), /3 (t+1)
        float scale = (bb < 8) ? (1.f / (2.f * 3.f * 8.f * 16384.f))
                               : (1.f / (2.f * 3.f * 16.f * 16384.f));
        atomicAdd(accum, v * scale);
    }
}

// Pass B: for each structure point, min over all 16384 gt points (chunked 512
// per block, combined via global atomicMin on uint-encoded nonneg floats).
__global__ __launch_bounds__(256) void chamfer_minB(
    const float* __restrict__ gt,
    const float* __restrict__ sp,
    const float* __restrict__ tgt,
    const float* __restrict__ tsp,
    unsigned int* __restrict__ minarr)   // [24*1024], init to large (0x7F bytes)
{
    __shared__ float4 s_ref[512];  // 8 KB
    const int bb    = blockIdx.x;   // 0..23
    const int chunk = blockIdx.y;   // 0..31 (512 gt points each)
    const float* refp = (bb < 8) ? (gt + (size_t)bb * NPTS * 3)
                                 : (tgt + (size_t)(bb - 8) * NPTS * 3);
    const float* qp   = (bb < 8) ? (sp + (size_t)bb * SPTS * 3)
                                 : (tsp + (size_t)(bb - 8) * SPTS * 3);
    const int tid = threadIdx.x;

    for (int i = tid; i < 512; i += 256) {
        int j = chunk * 512 + i;
        float x = refp[j * 3 + 0], y = refp[j * 3 + 1], z = refp[j * 3 + 2];
        s_ref[i] = make_float4(x, y, z, x * x + y * y + z * z);
    }
    __syncthreads();

    float qx2[4], qy2[4], qz2[4], qs[4], mn[4];
#pragma unroll
    for (int g = 0; g < 4; g++) {
        int q = g * 256 + tid;  // covers all 1024 structure points
        float x = qp[q * 3 + 0], y = qp[q * 3 + 1], z = qp[q * 3 + 2];
        qx2[g] = -2.f * x; qy2[g] = -2.f * y; qz2[g] = -2.f * z;
        qs[g] = x * x + y * y + z * z;
        mn[g] = 1e30f;
    }

#pragma unroll 2
    for (int j = 0; j < 512; j++) {
        float4 s = s_ref[j];
#pragma unroll
        for (int g = 0; g < 4; g++) {
            float d = fmaf(qx2[g], s.x, fmaf(qy2[g], s.y, fmaf(qz2[g], s.z, s.w)));
            mn[g] = fminf(mn[g], d);
        }
    }

#pragma unroll
    for (int g = 0; g < 4; g++) {
        int q = g * 256 + tid;
        float val = fmaxf(qs[g] + mn[g], 0.f);  // clamp tiny negatives for uint-ordered atomicMin
        atomicMin(&minarr[bb * SPTS + q], __float_as_uint(val));
    }
}

// Consistency: tmp[t,b,s,e] = sum_d structure[b,s,d]*trans[t,d,e]; MSE vs transed copies.
__global__ __launch_bounds__(256) void consistency_kernel(
    const float* __restrict__ sp,    // [8,1024,3]
    const float* __restrict__ tsp,   // [2,8,1024,3]
    const float* __restrict__ tm,    // [2,3,3]
    float* __restrict__ accum)
{
    int idx = blockIdx.x * 256 + threadIdx.x;  // 0..16383 over (t,b,s)
    int t = idx >> 13;         // /8192
    int bs = idx & 8191;
    const float* p = sp + (size_t)bs * 3;
    float x = p[0], y = p[1], z = p[2];
    const float* m = tm + t * 9;
    const float* q = tsp + (size_t)idx * 3;
    float acc = 0.f;
#pragma unroll
    for (int e = 0; e < 3; e++) {
        float v = fmaf(x, m[e], fmaf(y, m[3 + e], z * m[6 + e]));
        float d = v - q[e];
        acc = fmaf(d, d, acc);
    }
    for (int o = 32; o > 0; o >>= 1) acc += __shfl_down(acc, o, 64);
    if ((threadIdx.x & 63) == 0)
        atomicAdd(accum, acc * (1000.f / (2.f * 8.f * 1024.f * 3.f)));
}

__global__ __launch_bounds__(256) void finalize_kernel(
    const unsigned int* __restrict__ minarr,
    const float* __restrict__ accum,
    float* __restrict__ out)
{
    float s = 0.f;
    for (int i = threadIdx.x; i < 24 * 1024; i += 256) {
        float v = __uint_as_float(minarr[i]);
        int bb = i >> 10;
        float scale = (bb < 8) ? (1.f / (2.f * 3.f * 8.f * 1024.f))
                               : (1.f / (2.f * 3.f * 16.f * 1024.f));
        s += v * scale;
    }
    for (int o = 32; o > 0; o >>= 1) s += __shfl_down(s, o, 64);
    __shared__ float tmp[4];
    if ((threadIdx.x & 63) == 0) tmp[threadIdx.x >> 6] = s;
    __syncthreads();
    if (threadIdx.x == 0) out[0] = accum[0] + tmp[0] + tmp[1] + tmp[2] + tmp[3];
}

extern "C" void kernel_launch(void* const* d_in, const int* in_sizes, int n_in,
                              void* d_out, int out_size, void* d_ws, size_t ws_size,
                              hipStream_t stream) {
    const float* gt  = (const float*)d_in[0];  // gt_points [8,16384,3]
    const float* sp  = (const float*)d_in[1];  // structure_points [8,1024,3]
    const float* tgt = (const float*)d_in[2];  // transed_gt_points [2,8,16384,3]
    const float* tsp = (const float*)d_in[3];  // transed_structure_points [2,8,1024,3]
    const float* tm  = (const float*)d_in[4];  // trans_mats [2,3,3]
    float* out = (float*)d_out;

    float* accum = (float*)d_ws;
    unsigned int* minarr = (unsigned int*)((char*)d_ws + 64);

    hipMemsetAsync(accum, 0, 64, stream);
    hipMemsetAsync(minarr, 0x7F, 24 * 1024 * sizeof(unsigned int), stream);  // ~3.4e38 init

    chamfer_minA<<<dim3(24, 32), 256, 0, stream>>>(gt, sp, tgt, tsp, accum);
    chamfer_minB<<<dim3(24, 32), 256, 0, stream>>>(gt, sp, tgt, tsp, minarr);
    consistency_kernel<<<64, 256, 0, stream>>>(sp, tsp, tm, accum);
    finalize_kernel<<<1, 256, 0, stream>>>(minarr, accum, out);
}